// Round 7
// baseline (149.770 us; speedup 1.0000x reference)
//
#include <hip/hip_runtime.h>
#include <math.h>

// SSIM loss, fp32, N=16 C=3 H=W=512, 11x11 Gaussian sigma=1.5, zero-padded,
// separable — both blur passes on the MFMA pipe (16x16x32 bf16).
// R15 = R12 (best measured 45.7us: 16x64 tile, 5-wave swarm, GXD=8 XCD
// affinity, per-wave partials) with ONE change: coalesced staged loads.
//   R12's loads were 16 strided scalar dwords/thread (stride 2KB, 4B/lane,
//   4 lines per wave-instr) + heavy edge branch. The V-MFMA fragment (K=y)
//   needs column data per lane, so coalescing requires LDS redistribution:
//     stage: 32 rows x 84 cols f32 window ([tx0-8, tx0+75], 16B-aligned)
//            via ~2 dwordx4/thread/image, perfectly dense (1KB/wave-instr);
//     bar;  col-read: 8 ds_read_b32/image at stride 86 (2-way banks, free);
//     bar;  pass V / vb / pass H / epilogue BIT-IDENTICAL to R12.
//   Stage buffer unioned with vb (peak 22KB) -> same 6-block/CU residency.
//   Requests/wave 17 -> ~6; edge handling one masked path at stage time.
// Discriminating experiment: win => request/queueing efficiency was the
// wall; null => serial-latency wall (staging adds ~400cyc/chain).

#define IMG 512
#define TW 64
#define TH 16
#define GXD 8
#define GYD 32
#define GZD 48
#define NB (GXD * GYD * GZD)    // 12288
#define NB4 (NB * 4)            // per-wave partials
#define VBS 88                  // vb row stride in bf16 (16B-aligned)
#define SROW 86                 // staged row stride in f32 (84 cols + 2 pad)
#define NF4 21                  // float4s per staged row (84 cols)
#define NF4TOT (32 * NF4)       // 672 float4s per image
#define C1c 0.0001f
#define C2c 0.0009f
#define NTOTAL 12582912.0f
#define WS_NEED (1024 + (size_t)NB4 * 4)

typedef short bf16x8 __attribute__((ext_vector_type(8)));
typedef float f32x4 __attribute__((ext_vector_type(4)));
typedef float f32x2 __attribute__((ext_vector_type(2)));

struct GaussB { unsigned short gb[11]; };   // bf16 weights (host-RNE)

// pack bf16(a) low 16, bf16(b) high 16 — one v_perm_b32 (truncation)
__device__ __forceinline__ unsigned int pkbf(float a, float b) {
    return __builtin_amdgcn_perm(__float_as_uint(b), __float_as_uint(a),
                                 0x07060302u);
}

// ---------------- staged load helpers --------------------------------------

// masked float4 load of pixels [gy][gx0..gx0+3]; gx0 is 16B-aligned by
// construction (tx0-8+4*c4). Zero outside the image.
__device__ __forceinline__ float4 ldf4(const float* __restrict__ base,
                                       int gy, int gx0) {
    float4 v = make_float4(0.f, 0.f, 0.f, 0.f);
    if ((unsigned)gy < (unsigned)IMG) {
        if ((unsigned)gx0 <= (unsigned)(IMG - 4)) {          // fully inside
            v = *(const float4*)(base + gy * IMG + gx0);
        } else {                                             // x-edge
            float* e = (float*)&v;
            #pragma unroll
            for (int k = 0; k < 4; ++k) {
                int gx = gx0 + k;
                if ((unsigned)gx < (unsigned)IMG) e[k] = base[gy * IMG + gx];
            }
        }
    }
    return v;
}

// write float4 into stage row r, f4-slot c4 as 2x ds_write_b64 (8B-aligned)
__device__ __forceinline__ void stw(float* arr, int r, int c4, float4 v) {
    float* p = arr + r * SROW + 4 * c4;
    *(float2*)p       = make_float2(v.x, v.y);
    *(float2*)(p + 2) = make_float2(v.z, v.w);
}

// ---------------- pass bodies (bit-identical to R12) -----------------------

__device__ __forceinline__ void pass_v_body(
    const float (&pv)[8], const float (&tv)[8], bf16x8 wfrag,
    unsigned short (*vb)[16][VBS], int n16, int vcol) {
    const f32x4 z = {0.0f, 0.0f, 0.0f, 0.0f};
    const f32x2 halfv = {0.5f, 0.5f};
    f32x2 p2[4], t2[4];
    #pragma unroll
    for (int h = 0; h < 4; ++h) {
        f32x2 pr = {pv[2*h], pv[2*h+1]};
        f32x2 tr = {tv[2*h], tv[2*h+1]};
        p2[h] = pr * halfv + halfv;     // v_pk_fma_f32
        t2[h] = tr * halfv + halfv;
    }
    #pragma unroll
    for (int ch = 0; ch < 5; ++ch) {
        union { bf16x8 v; unsigned int u[4]; } f;
        #pragma unroll
        for (int h = 0; h < 4; ++h) {
            f32x2 q;
            if      (ch == 0) q = p2[h];
            else if (ch == 1) q = t2[h];
            else if (ch == 2) q = p2[h] * p2[h];   // v_pk_mul_f32
            else if (ch == 3) q = t2[h] * t2[h];
            else              q = p2[h] * t2[h];
            f.u[h] = pkbf(q.x, q.y);
        }
        f32x4 d = __builtin_amdgcn_mfma_f32_16x16x32_bf16(f.v, wfrag, z, 0, 0, 0);
        union { ushort4 s; unsigned int u[2]; } pk;
        pk.u[0] = pkbf(d[0], d[1]);
        pk.u[1] = pkbf(d[2], d[3]);
        *(ushort4*)&vb[ch][n16][vcol] = pk.s;
    }
}

__device__ __forceinline__ float pass_h_body(
    unsigned short (*vb)[16][VBS], bf16x8 wfrag, int n16, int quad, int w) {
    const f32x4 z = {0.0f, 0.0f, 0.0f, 0.0f};
    float lsum = 0.0f;
    f32x4 r[5];
    #pragma unroll
    for (int ch = 0; ch < 5; ++ch) {
        bf16x8 a = *(const bf16x8*)&vb[ch][n16][16 * w + 8 * quad];
        r[ch] = __builtin_amdgcn_mfma_f32_16x16x32_bf16(a, wfrag, z, 0, 0, 0);
    }
    const f32x2 twov = {2.0f, 2.0f};
    const f32x2 c1v  = {C1c, C1c};
    const f32x2 c2v  = {C2c, C2c};
    #pragma unroll
    for (int jj = 0; jj < 2; ++jj) {
        f32x2 mp  = {r[0][2*jj], r[0][2*jj+1]};
        f32x2 mt  = {r[1][2*jj], r[1][2*jj+1]};
        f32x2 epp = {r[2][2*jj], r[2][2*jj+1]};
        f32x2 ett = {r[3][2*jj], r[3][2*jj+1]};
        f32x2 ept = {r[4][2*jj], r[4][2*jj+1]};
        f32x2 mp2 = mp * mp;
        f32x2 mt2 = mt * mt;
        f32x2 mpt = mp * mt;
        f32x2 sp_ = epp - mp2;
        f32x2 st_ = ett - mt2;
        f32x2 spt = ept - mpt;
        f32x2 num = (mpt * twov + c1v) * (spt * twov + c2v);
        f32x2 den = (mp2 + mt2 + c1v) * (sp_ + st_ + c2v);
        lsum = fmaf(num.x, __builtin_amdgcn_rcpf(den.x), lsum);
        lsum = fmaf(num.y, __builtin_amdgcn_rcpf(den.y), lsum);
    }
    return lsum;
}

// ---------------- main kernel, workspace path (R15) ------------------------

__global__ __launch_bounds__(320, 6) void ssim_main_ws(
    const float* __restrict__ pred,
    const float* __restrict__ target,
    const unsigned short* __restrict__ wtab,   // 16x32 bf16 W matrix in ws
    float* __restrict__ partials)              // NB4 per-wave partials
{
    // stage buffers (2 x 32 x 86 f32 = 22016 B) unioned with vb (14080 B):
    // ps/ts are dead once column reads complete; vb lives after barrier 2.
    __shared__ float sbuf[2 * 32 * SROW];
    float* ps = sbuf;
    float* ts = sbuf + 32 * SROW;
    auto vb = reinterpret_cast<unsigned short (*)[16][VBS]>(sbuf);

    const int tid  = threadIdx.x;
    const int w    = tid >> 6;        // wave 0..4 = V-chunk id
    const int lane = tid & 63;
    const int quad = lane >> 4;
    const int n16  = lane & 15;
    const int tx0  = blockIdx.x * TW;
    const int ty0  = blockIdx.y * TH;
    const float* __restrict__ pbase = pred   + (size_t)blockIdx.z * (IMG * IMG);
    const float* __restrict__ tbase = target + (size_t)blockIdx.z * (IMG * IMG);

    // wfrag: one L2-hot 16B load, overlaps the stage loads
    const bf16x8 wfrag = *(const bf16x8*)(wtab + n16 * 32 + quad * 8);

    // ---- stage: rows ty0-5..ty0+26, cols tx0-8..tx0+75 (16B-aligned) ----
    // 672 f4 per image over 320 threads (threads 0-31 take a third f4).
    for (int id = tid; id < NF4TOT; id += 320) {
        const int r  = id / NF4;
        const int c4 = id - r * NF4;
        const int gy  = ty0 - 5 + r;
        const int gx0 = tx0 - 8 + 4 * c4;
        float4 pvv = ldf4(pbase, gy, gx0);
        float4 tvv = ldf4(tbase, gy, gx0);
        stw(ps, r, c4, pvv);
        stw(ts, r, c4, tvv);
    }
    __syncthreads();

    // ---- column reads: lane's 8-row column (staged col 3+16w+n16) ----
    // bank = (16q + col + 86j) % 32 -> exactly 2 lanes/bank (free, m136)
    const int col = 3 + 16 * w + n16;   // gx = tx0-5+16w+n16 = (tx0-8)+col
    float pv[8], tv[8];
    {
        const float* pc = ps + (quad * 8) * SROW + col;
        const float* tc = ts + (quad * 8) * SROW + col;
        #pragma unroll
        for (int j = 0; j < 8; ++j) {
            pv[j] = pc[j * SROW];
            tv[j] = tc[j * SROW];
        }
    }
    __syncthreads();   // stage reads complete; vb may overwrite sbuf

    pass_v_body(pv, tv, wfrag, vb, n16, 16 * w + 4 * quad);
    __syncthreads();

    float lsum = 0.0f;
    if (w < 4)
        lsum = pass_h_body(vb, wfrag, n16, quad, w);

    #pragma unroll
    for (int off = 32; off > 0; off >>= 1)
        lsum += __shfl_down(lsum, off, 64);
    if (lane == 0 && w < 4) {
        int bid = blockIdx.x + GXD * (blockIdx.y + GYD * blockIdx.z);
        partials[bid * 4 + w] = lsum;
    }
}

// W-table init on device
__global__ void ssim_winit(unsigned short* __restrict__ wtab, GaussB gwb) {
    int idx = threadIdx.x;            // 512 threads
    int i = idx >> 5, k = idx & 31, d = k - i;
    wtab[idx] = (d >= 0 && d <= 10) ? gwb.gb[d] : 0;
}

// ---------------- atomic fallback (ws too small) ---------------------------

__global__ __launch_bounds__(320, 6) void ssim_main_atomic(
    const float* __restrict__ pred,
    const float* __restrict__ target,
    float* __restrict__ sink,
    GaussB gwb)
{
    __shared__ float sbuf[2 * 32 * SROW];
    __shared__ unsigned short Wmat[16][32];
    __shared__ float red[5];
    float* ps = sbuf;
    float* ts = sbuf + 32 * SROW;
    auto vb = reinterpret_cast<unsigned short (*)[16][VBS]>(sbuf);

    const int tid  = threadIdx.x;
    const int w    = tid >> 6;
    const int lane = tid & 63;
    const int quad = lane >> 4;
    const int n16  = lane & 15;
    const int tx0  = blockIdx.x * TW;
    const int ty0  = blockIdx.y * TH;
    const float* __restrict__ pbase = pred   + (size_t)blockIdx.z * (IMG * IMG);
    const float* __restrict__ tbase = target + (size_t)blockIdx.z * (IMG * IMG);

    for (int idx = tid; idx < 512; idx += 320) {
        int i = idx >> 5, k = idx & 31, d = k - i;
        Wmat[i][k] = (d >= 0 && d <= 10) ? gwb.gb[d] : 0;
    }

    for (int id = tid; id < NF4TOT; id += 320) {
        const int r  = id / NF4;
        const int c4 = id - r * NF4;
        const int gy  = ty0 - 5 + r;
        const int gx0 = tx0 - 8 + 4 * c4;
        float4 pvv = ldf4(pbase, gy, gx0);
        float4 tvv = ldf4(tbase, gy, gx0);
        stw(ps, r, c4, pvv);
        stw(ts, r, c4, tvv);
    }
    __syncthreads();
    const bf16x8 wfrag = *(const bf16x8*)&Wmat[n16][quad * 8];

    const int col = 3 + 16 * w + n16;
    float pv[8], tv[8];
    {
        const float* pc = ps + (quad * 8) * SROW + col;
        const float* tc = ts + (quad * 8) * SROW + col;
        #pragma unroll
        for (int j = 0; j < 8; ++j) {
            pv[j] = pc[j * SROW];
            tv[j] = tc[j * SROW];
        }
    }
    __syncthreads();

    pass_v_body(pv, tv, wfrag, vb, n16, 16 * w + 4 * quad);
    __syncthreads();

    float lsum = 0.0f;
    if (w < 4)
        lsum = pass_h_body(vb, wfrag, n16, quad, w);

    #pragma unroll
    for (int off = 32; off > 0; off >>= 1)
        lsum += __shfl_down(lsum, off, 64);
    if (lane == 0) red[w] = lsum;
    __syncthreads();
    if (tid == 0)
        atomicAdd(sink, red[0] + red[1] + red[2] + red[3]);
}

// ---------------- reductions ----------------------------------------------

__global__ __launch_bounds__(1024) void ssim_reduce(const float* __restrict__ partials,
                                                    float* __restrict__ out)
{
    __shared__ float red[16];
    const int tid = threadIdx.x;
    float s = 0.0f;
    const float4* p4 = (const float4*)partials;
    #pragma unroll
    for (int j = 0; j < NB4 / 4096; ++j) {   // 49152/4 = 12288 f4 / 1024
        float4 v = p4[tid + 1024 * j];
        s += v.x + v.y + v.z + v.w;
    }
    #pragma unroll
    for (int off = 32; off > 0; off >>= 1)
        s += __shfl_down(s, off, 64);
    if ((tid & 63) == 0) red[tid >> 6] = s;
    __syncthreads();
    if (tid == 0) {
        float t = 0.0f;
        #pragma unroll
        for (int k = 0; k < 16; ++k) t += red[k];
        out[0] = 1.0f - t / NTOTAL;
    }
}

__global__ void ssim_zero(float* accum) { accum[0] = 0.0f; }
__global__ void ssim_final(const float* accum, float* out) {
    out[0] = 1.0f - accum[0] / NTOTAL;
}

// ---------------- host ----------------------------------------------------

extern "C" void kernel_launch(void* const* d_in, const int* in_sizes, int n_in,
                              void* d_out, int out_size, void* d_ws, size_t ws_size,
                              hipStream_t stream) {
    const float* pred   = (const float*)d_in[0];
    const float* target = (const float*)d_in[1];
    float* out = (float*)d_out;

    // Gaussian weights in double, RNE-rounded to bf16 on host
    GaussB gwb;
    double vals[11], s = 0.0;
    for (int i = 0; i < 11; ++i) {
        double d = (double)i - 5.0;
        vals[i] = exp(-(d * d) / (2.0 * 1.5 * 1.5));
        s += vals[i];
    }
    for (int i = 0; i < 11; ++i) {
        float f = (float)(vals[i] / s);
        unsigned int u;
        __builtin_memcpy(&u, &f, 4);
        unsigned int rounded = (u + 0x7FFFu + ((u >> 16) & 1u)) >> 16;  // RNE
        gwb.gb[i] = (unsigned short)rounded;
    }

    dim3 grid(GXD, GYD, GZD);   // 8 x 32 x 48 = 12288 blocks
    if (ws_size >= WS_NEED) {
        unsigned short* wtab = (unsigned short*)d_ws;            // 1 KB
        float* partials = (float*)((char*)d_ws + 1024);          // NB4 floats
        ssim_winit<<<1, 512, 0, stream>>>(wtab, gwb);
        ssim_main_ws<<<grid, 320, 0, stream>>>(pred, target, wtab, partials);
        ssim_reduce<<<1, 1024, 0, stream>>>(partials, out);
    } else {
        float* accum = (float*)d_ws;
        ssim_zero<<<1, 1, 0, stream>>>(accum);
        ssim_main_atomic<<<grid, 320, 0, stream>>>(pred, target, accum, gwb);
        ssim_final<<<1, 1, 0, stream>>>(accum, out);
    }
}

// Round 8
// 138.749 us; speedup vs baseline: 1.0794x; 1.0794x over previous
//
#include <hip/hip_runtime.h>
#include <math.h>

// SSIM loss, fp32, N=16 C=3 H=W=512, 11x11 Gaussian sigma=1.5, zero-padded,
// separable — both blur passes on the MFMA pipe (16x16x32 bf16).
// R16 = R12 (best measured 45.7us) with a 2-tile y-unroll for memory-level
// parallelism at constant residency:
//   - block = 32 rows x 64 cols (two R12 tiles), 320 thr, grid 8x16x48.
//   - ALL 32 pixel loads (both tiles) issued up-front; wfrag issued FIRST
//     so its vmcnt wait doesn't force a full drain. Tile-1's 16 loads stay
//     in flight across V0/H0 (raw lgkmcnt(0)+s_barrier, no vmcnt(0) drain
//     — m139/m218: counted vmcnt survives s_barrier) and land under
//     ~1500 cyc of compute. Memory port busy ~2/3 of block life vs ~1/4.
//   - 16 overlap rows between tiles become same-CU L1 hits (FETCH -=
//     a little); y-neighbor blocks differ by GXD=8 == XCD count -> vertical
//     halo stays XCD-L2-hot (R11 lesson). FETCH stays compulsory ~90MB.
//   - launch_bounds(320,8) pins VGPR<=64 -> 6 blocks/CU stay resident
//     (R14 lesson: VGPR growth halves residency). Watch WRITE_SIZE for
//     spill evidence (R6 lesson).
//   - per-block fixed overhead (wfrag load, reduce, store) amortized 2x.
// Per-pixel math / fragments / vb layout BIT-IDENTICAL to R12.

#define IMG 512
#define TW 64
#define TH 32                   // 2 sub-tiles of 16 rows
#define GXD 8
#define GYD 16
#define GZD 48
#define NB (GXD * GYD * GZD)    // 6144
#define NB4 (NB * 4)            // per-wave partials
#define VBS 88                  // vb row stride in bf16 (16B-aligned)
#define C1c 0.0001f
#define C2c 0.0009f
#define NTOTAL 12582912.0f
#define WS_NEED (1024 + (size_t)NB4 * 4)

// raw barrier with LDS-publish semantics: drain own-wave LDS ops, fence,
// barrier. vmcnt deliberately NOT drained — prefetched globals stay in
// flight. The "memory" clobber also pins global loads issued above it
// (they cannot sink past a memory-clobbering asm).
#define LGKM_BAR() do {                                            \
    asm volatile("s_waitcnt lgkmcnt(0)" ::: "memory");             \
    __builtin_amdgcn_s_barrier();                                  \
    asm volatile("" ::: "memory");                                 \
} while (0)

typedef short bf16x8 __attribute__((ext_vector_type(8)));
typedef float f32x4 __attribute__((ext_vector_type(4)));
typedef float f32x2 __attribute__((ext_vector_type(2)));

struct GaussB { unsigned short gb[11]; };   // bf16 weights (host-RNE)

// pack bf16(a) low 16, bf16(b) high 16 — one v_perm_b32 (truncation)
__device__ __forceinline__ unsigned int pkbf(float a, float b) {
    return __builtin_amdgcn_perm(__float_as_uint(b), __float_as_uint(a),
                                 0x07060302u);
}

// ---------------- shared device pieces (identical math to R12) -------------

__device__ __forceinline__ void load_px(const float* __restrict__ pbase,
                                        const float* __restrict__ tbase,
                                        int gx, bool xin, int gy0,
                                        float (&pv)[8], float (&tv)[8]) {
    const bool ok = xin & (gy0 >= 0) & (gy0 <= IMG - 8);
    if (ok) {
        const float* pp = pbase + gy0 * IMG + gx;
        const float* tp = tbase + gy0 * IMG + gx;
        #pragma unroll
        for (int j = 0; j < 8; ++j) {
            pv[j] = pp[j * IMG];
            tv[j] = tp[j * IMG];
        }
    } else {
        #pragma unroll
        for (int j = 0; j < 8; ++j) {
            int gy = gy0 + j;
            bool in = xin && ((unsigned)gy < (unsigned)IMG);
            int idx = in ? (gy * IMG + gx) : 0;
            float a = pbase[idx];
            float b = tbase[idx];
            pv[j] = in ? a : 0.0f;
            tv[j] = in ? b : 0.0f;
        }
    }
}

__device__ __forceinline__ void pass_v_body(
    const float (&pv)[8], const float (&tv)[8], bf16x8 wfrag,
    unsigned short (*vb)[16][VBS], int n16, int vcol) {
    const f32x4 z = {0.0f, 0.0f, 0.0f, 0.0f};
    const f32x2 halfv = {0.5f, 0.5f};
    f32x2 p2[4], t2[4];
    #pragma unroll
    for (int h = 0; h < 4; ++h) {
        f32x2 pr = {pv[2*h], pv[2*h+1]};
        f32x2 tr = {tv[2*h], tv[2*h+1]};
        p2[h] = pr * halfv + halfv;     // v_pk_fma_f32
        t2[h] = tr * halfv + halfv;
    }
    #pragma unroll
    for (int ch = 0; ch < 5; ++ch) {
        union { bf16x8 v; unsigned int u[4]; } f;
        #pragma unroll
        for (int h = 0; h < 4; ++h) {
            f32x2 q;
            if      (ch == 0) q = p2[h];
            else if (ch == 1) q = t2[h];
            else if (ch == 2) q = p2[h] * p2[h];   // v_pk_mul_f32
            else if (ch == 3) q = t2[h] * t2[h];
            else              q = p2[h] * t2[h];
            f.u[h] = pkbf(q.x, q.y);
        }
        f32x4 d = __builtin_amdgcn_mfma_f32_16x16x32_bf16(f.v, wfrag, z, 0, 0, 0);
        union { ushort4 s; unsigned int u[2]; } pk;
        pk.u[0] = pkbf(d[0], d[1]);
        pk.u[1] = pkbf(d[2], d[3]);
        *(ushort4*)&vb[ch][n16][vcol] = pk.s;
    }
}

__device__ __forceinline__ float pass_h_body(
    unsigned short (*vb)[16][VBS], bf16x8 wfrag, int n16, int quad, int w) {
    const f32x4 z = {0.0f, 0.0f, 0.0f, 0.0f};
    float lsum = 0.0f;
    f32x4 r[5];
    #pragma unroll
    for (int ch = 0; ch < 5; ++ch) {
        bf16x8 a = *(const bf16x8*)&vb[ch][n16][16 * w + 8 * quad];
        r[ch] = __builtin_amdgcn_mfma_f32_16x16x32_bf16(a, wfrag, z, 0, 0, 0);
    }
    const f32x2 twov = {2.0f, 2.0f};
    const f32x2 c1v  = {C1c, C1c};
    const f32x2 c2v  = {C2c, C2c};
    #pragma unroll
    for (int jj = 0; jj < 2; ++jj) {
        f32x2 mp  = {r[0][2*jj], r[0][2*jj+1]};
        f32x2 mt  = {r[1][2*jj], r[1][2*jj+1]};
        f32x2 epp = {r[2][2*jj], r[2][2*jj+1]};
        f32x2 ett = {r[3][2*jj], r[3][2*jj+1]};
        f32x2 ept = {r[4][2*jj], r[4][2*jj+1]};
        f32x2 mp2 = mp * mp;
        f32x2 mt2 = mt * mt;
        f32x2 mpt = mp * mt;
        f32x2 sp_ = epp - mp2;
        f32x2 st_ = ett - mt2;
        f32x2 spt = ept - mpt;
        f32x2 num = (mpt * twov + c1v) * (spt * twov + c2v);
        f32x2 den = (mp2 + mt2 + c1v) * (sp_ + st_ + c2v);
        lsum = fmaf(num.x, __builtin_amdgcn_rcpf(den.x), lsum);
        lsum = fmaf(num.y, __builtin_amdgcn_rcpf(den.y), lsum);
    }
    return lsum;
}

// ---------------- main kernel, workspace path (R16) ------------------------

__global__ __launch_bounds__(320, 8) void ssim_main_ws(
    const float* __restrict__ pred,
    const float* __restrict__ target,
    const unsigned short* __restrict__ wtab,   // 16x32 bf16 W matrix in ws
    float* __restrict__ partials)              // NB4 per-wave partials
{
    __shared__ unsigned short vb[5][16][VBS];     // 14080 B (shared by tiles)

    const int tid  = threadIdx.x;
    const int w    = tid >> 6;        // wave 0..4 = V-chunk id
    const int lane = tid & 63;
    const int quad = lane >> 4;
    const int n16  = lane & 15;
    const int tx0  = blockIdx.x * TW;
    const int ty0  = blockIdx.y * TH;              // 32-row block
    const float* __restrict__ pbase = pred   + (size_t)blockIdx.z * (IMG * IMG);
    const float* __restrict__ tbase = target + (size_t)blockIdx.z * (IMG * IMG);

    const int gx   = tx0 - 5 + 16 * w + n16;   // this lane's input column
    const bool xin = (unsigned)gx < (unsigned)IMG;
    const int gy0a = ty0 - 5 + quad * 8;       // tile 0 rows
    const int gy0b = ty0 + 11 + quad * 8;      // tile 1 rows (ty0+16-5)
    const int vcol = 16 * w + 4 * quad;

    // wfrag FIRST: its vmcnt wait then never forces a full drain
    const bf16x8 wfrag = *(const bf16x8*)(wtab + n16 * 32 + quad * 8);

    // both tiles' loads up-front: 32 outstanding per thread-chain
    float pv0[8], tv0[8], pv1[8], tv1[8];
    load_px(pbase, tbase, gx, xin, gy0a, pv0, tv0);
    load_px(pbase, tbase, gx, xin, gy0b, pv1, tv1);

    // ---- tile 0 ----
    pass_v_body(pv0, tv0, wfrag, vb, n16, vcol);   // counted vmcnt: tile0 only
    LGKM_BAR();                                    // vb published, t1 in flight
    float lsum = 0.0f;
    if (w < 4)
        lsum = pass_h_body(vb, wfrag, n16, quad, w);
    LGKM_BAR();                                    // H0 reads drained

    // ---- tile 1 ----
    pass_v_body(pv1, tv1, wfrag, vb, n16, vcol);   // loads landed under V0+H0
    LGKM_BAR();
    if (w < 4)
        lsum += pass_h_body(vb, wfrag, n16, quad, w);

    // ---- per-wave reduction + store ----
    #pragma unroll
    for (int off = 32; off > 0; off >>= 1)
        lsum += __shfl_down(lsum, off, 64);
    if (lane == 0 && w < 4) {
        int bid = blockIdx.x + GXD * (blockIdx.y + GYD * blockIdx.z);
        partials[bid * 4 + w] = lsum;
    }
}

// W-table init on device
__global__ void ssim_winit(unsigned short* __restrict__ wtab, GaussB gwb) {
    int idx = threadIdx.x;            // 512 threads
    int i = idx >> 5, k = idx & 31, d = k - i;
    wtab[idx] = (d >= 0 && d <= 10) ? gwb.gb[d] : 0;
}

// ---------------- atomic fallback (ws too small) ---------------------------

__global__ __launch_bounds__(320, 8) void ssim_main_atomic(
    const float* __restrict__ pred,
    const float* __restrict__ target,
    float* __restrict__ sink,
    GaussB gwb)
{
    __shared__ unsigned short Wmat[16][32];
    __shared__ unsigned short vb[5][16][VBS];
    __shared__ float red[5];

    const int tid  = threadIdx.x;
    const int w    = tid >> 6;
    const int lane = tid & 63;
    const int quad = lane >> 4;
    const int n16  = lane & 15;
    const int tx0  = blockIdx.x * TW;
    const int ty0  = blockIdx.y * TH;
    const float* __restrict__ pbase = pred   + (size_t)blockIdx.z * (IMG * IMG);
    const float* __restrict__ tbase = target + (size_t)blockIdx.z * (IMG * IMG);

    const int gx   = tx0 - 5 + 16 * w + n16;
    const bool xin = (unsigned)gx < (unsigned)IMG;
    const int gy0a = ty0 - 5 + quad * 8;
    const int gy0b = ty0 + 11 + quad * 8;
    const int vcol = 16 * w + 4 * quad;

    float pv0[8], tv0[8], pv1[8], tv1[8];
    load_px(pbase, tbase, gx, xin, gy0a, pv0, tv0);
    load_px(pbase, tbase, gx, xin, gy0b, pv1, tv1);

    for (int idx = tid; idx < 512; idx += 320) {
        int i = idx >> 5, k = idx & 31, d = k - i;
        Wmat[i][k] = (d >= 0 && d <= 10) ? gwb.gb[d] : 0;
    }
    __syncthreads();
    const bf16x8 wfrag = *(const bf16x8*)&Wmat[n16][quad * 8];

    pass_v_body(pv0, tv0, wfrag, vb, n16, vcol);
    __syncthreads();
    float lsum = 0.0f;
    if (w < 4)
        lsum = pass_h_body(vb, wfrag, n16, quad, w);
    __syncthreads();
    pass_v_body(pv1, tv1, wfrag, vb, n16, vcol);
    __syncthreads();
    if (w < 4)
        lsum += pass_h_body(vb, wfrag, n16, quad, w);

    #pragma unroll
    for (int off = 32; off > 0; off >>= 1)
        lsum += __shfl_down(lsum, off, 64);
    if (lane == 0) red[w] = lsum;
    __syncthreads();
    if (tid == 0)
        atomicAdd(sink, red[0] + red[1] + red[2] + red[3]);
}

// ---------------- reductions ----------------------------------------------

__global__ __launch_bounds__(1024) void ssim_reduce(const float* __restrict__ partials,
                                                    float* __restrict__ out)
{
    __shared__ float red[16];
    const int tid = threadIdx.x;
    float s = 0.0f;
    const float4* p4 = (const float4*)partials;
    #pragma unroll
    for (int j = 0; j < NB4 / 4096; ++j) {   // 24576/4 = 6144 f4 / 1024
        float4 v = p4[tid + 1024 * j];
        s += v.x + v.y + v.z + v.w;
    }
    #pragma unroll
    for (int off = 32; off > 0; off >>= 1)
        s += __shfl_down(s, off, 64);
    if ((tid & 63) == 0) red[tid >> 6] = s;
    __syncthreads();
    if (tid == 0) {
        float t = 0.0f;
        #pragma unroll
        for (int k = 0; k < 16; ++k) t += red[k];
        out[0] = 1.0f - t / NTOTAL;
    }
}

__global__ void ssim_zero(float* accum) { accum[0] = 0.0f; }
__global__ void ssim_final(const float* accum, float* out) {
    out[0] = 1.0f - accum[0] / NTOTAL;
}

// ---------------- host ----------------------------------------------------

extern "C" void kernel_launch(void* const* d_in, const int* in_sizes, int n_in,
                              void* d_out, int out_size, void* d_ws, size_t ws_size,
                              hipStream_t stream) {
    const float* pred   = (const float*)d_in[0];
    const float* target = (const float*)d_in[1];
    float* out = (float*)d_out;

    // Gaussian weights in double, RNE-rounded to bf16 on host
    GaussB gwb;
    double vals[11], s = 0.0;
    for (int i = 0; i < 11; ++i) {
        double d = (double)i - 5.0;
        vals[i] = exp(-(d * d) / (2.0 * 1.5 * 1.5));
        s += vals[i];
    }
    for (int i = 0; i < 11; ++i) {
        float f = (float)(vals[i] / s);
        unsigned int u;
        __builtin_memcpy(&u, &f, 4);
        unsigned int rounded = (u + 0x7FFFu + ((u >> 16) & 1u)) >> 16;  // RNE
        gwb.gb[i] = (unsigned short)rounded;
    }

    dim3 grid(GXD, GYD, GZD);   // 8 x 16 x 48 = 6144 blocks (32-row tiles)
    if (ws_size >= WS_NEED) {
        unsigned short* wtab = (unsigned short*)d_ws;            // 1 KB
        float* partials = (float*)((char*)d_ws + 1024);          // NB4 floats
        ssim_winit<<<1, 512, 0, stream>>>(wtab, gwb);
        ssim_main_ws<<<grid, 320, 0, stream>>>(pred, target, wtab, partials);
        ssim_reduce<<<1, 1024, 0, stream>>>(partials, out);
    } else {
        float* accum = (float*)d_ws;
        ssim_zero<<<1, 1, 0, stream>>>(accum);
        ssim_main_atomic<<<grid, 320, 0, stream>>>(pred, target, accum, gwb);
        ssim_final<<<1, 1, 0, stream>>>(accum, out);
    }
}